// Round 8
// baseline (547.112 us; speedup 1.0000x reference)
//
#include <hip/hip_runtime.h>
#include <math.h>

namespace {
constexpr int BB = 8;
constexpr int CH = 256;
constexpr int CQ = 32;
constexpr int NN = 4096;
}

typedef float f32x4 __attribute__((ext_vector_type(4)));
typedef short bf16x8 __attribute__((ext_vector_type(8)));
typedef unsigned short us8 __attribute__((ext_vector_type(8)));

#define MFMA16(a, b, c) __builtin_amdgcn_mfma_f32_16x16x32_bf16(a, b, c, 0, 0, 0)
#define LOG2E 1.4426950408889634f

__device__ __forceinline__ unsigned short f2bf(float x) {
    unsigned int u = __float_as_uint(x);
    u += 0x7fffu + ((u >> 16) & 1u);
    return (unsigned short)(u >> 16);
}
__device__ __forceinline__ float bf2f(unsigned short h) {
    return __uint_as_float(((unsigned int)h) << 16);
}
__device__ __forceinline__ void gload16(const void* g, void* l) {
    __builtin_amdgcn_global_load_lds(
        (const __attribute__((address_space(1))) unsigned int*)g,
        (__attribute__((address_space(3))) unsigned int*)l, 16, 0, 0);
}

// ---------------------------------------------------------------------------
// Kernel 0: split W (wq|wk|wv concat, 320x256) into bf16 hi/lo.
// ---------------------------------------------------------------------------
__global__ __launch_bounds__(256) void wsplit_kernel(
    const float* __restrict__ wq, const float* __restrict__ wk,
    const float* __restrict__ wv,
    unsigned short* __restrict__ wh, unsigned short* __restrict__ wl)
{
    int idx = blockIdx.x * 256 + threadIdx.x;   // 0..81919
    float v;
    if (idx < 8192)       v = wq[idx];
    else if (idx < 16384) v = wk[idx - 8192];
    else                  v = wv[idx - 16384];
    unsigned short hi = f2bf(v);
    wh[idx] = hi;
    wl[idx] = f2bf(v - bf2f(hi));
}

// ---------------------------------------------------------------------------
// Kernel 1: transpose+split X [b][256c][4096n] fp32 -> Xh/Xl [b][n][256c] bf16.
// ---------------------------------------------------------------------------
__global__ __launch_bounds__(256) void transpose_kernel(
    const float* __restrict__ x,
    unsigned short* __restrict__ xh, unsigned short* __restrict__ xl)
{
    __shared__ float xf[64 * 68];                 // fp32 tile, padded rows
    __shared__ unsigned short hs[64 * 80];        // bf16 [n][64c] padded
    __shared__ unsigned short ls[64 * 80];
    const int t  = threadIdx.x;
    const int b  = blockIdx.x >> 8;
    const int tl = blockIdx.x & 255;
    const int c0 = (tl >> 6) * 64;
    const int n0 = (tl & 63) * 64;

    #pragma unroll
    for (int i = 0; i < 4; ++i) {
        int idx = i * 256 + t;
        int c = idx >> 4, nf = idx & 15;
        float4 v4 = *(const float4*)(x + ((size_t)(b * 256 + c0 + c)) * NN + n0 + nf * 4);
        *(float4*)(xf + c * 68 + nf * 4) = v4;
    }
    __syncthreads();

    const int n = t & 63;
    #pragma unroll
    for (int loop = 0; loop < 2; ++loop) {
        int chunk = (t >> 6) + 4 * loop;          // 0..7 (8 c's each)
        us8 h8, l8;
        #pragma unroll
        for (int j = 0; j < 8; ++j) {
            float v = xf[(chunk * 8 + j) * 68 + n];
            unsigned short hi = f2bf(v);
            h8[j] = hi;
            l8[j] = f2bf(v - bf2f(hi));
        }
        *(us8*)(hs + n * 80 + chunk * 8) = h8;
        *(us8*)(ls + n * 80 + chunk * 8) = l8;
    }
    __syncthreads();

    {
        int rn = t >> 2, piece = t & 3;
        size_t grow = ((size_t)(b * NN + n0 + rn)) * 256 + c0 + piece * 16;
        *(us8*)(xh + grow)     = *(const us8*)(hs + rn * 80 + piece * 16);
        *(us8*)(xh + grow + 8) = *(const us8*)(hs + rn * 80 + piece * 16 + 8);
        *(us8*)(xl + grow)     = *(const us8*)(ls + rn * 80 + piece * 16);
        *(us8*)(xl + grow + 8) = *(const us8*)(ls + rn * 80 + piece * 16 + 8);
    }
}

// ---------------------------------------------------------------------------
// Kernel 2: proj GEMM via MFMA (unchanged; Q pre-scaled by log2e).
// ---------------------------------------------------------------------------
#define PJ_XL 32768
#define PJ_VE 16384
__global__ __launch_bounds__(256, 2) void proj_kernel(
    const unsigned short* __restrict__ xh, const unsigned short* __restrict__ xl,
    const unsigned short* __restrict__ wh, const unsigned short* __restrict__ wl,
    const float* __restrict__ bq, const float* __restrict__ bk,
    const float* __restrict__ bv,
    unsigned short* __restrict__ qh, unsigned short* __restrict__ ql,
    unsigned short* __restrict__ kh, unsigned short* __restrict__ kl,
    unsigned short* __restrict__ vt)
{
    __shared__ __align__(16) unsigned char smem[65536];
    const int t    = threadIdx.x;
    const int lane = t & 63;
    const int w    = t >> 6;
    const int l16  = lane & 15;
    const int quad = lane >> 4;
    const int b    = blockIdx.x >> 6;
    const int n0   = (blockIdx.x & 63) << 6;

    const unsigned char* xhB = (const unsigned char*)(xh + ((size_t)b * NN + n0) * 256);
    const unsigned char* xlB = (const unsigned char*)(xl + ((size_t)b * NN + n0) * 256);
    #pragma unroll
    for (int j = 0; j < 8; ++j) {
        int idx = j * 256 + t;
        int r = idx >> 5, cl = idx & 31;
        int cg = cl ^ (r & 7);
        gload16(xhB + (size_t)r * 512 + cg * 16, smem + idx * 16);
        gload16(xlB + (size_t)r * 512 + cg * 16, smem + PJ_XL + idx * 16);
    }
    __syncthreads();

    f32x4 acc[5][4] = {};
    #pragma unroll 1
    for (int kc = 0; kc < 8; ++kc) {
        bf16x8 ah[5], al[5];
        #pragma unroll
        for (int i = 0; i < 5; ++i) {
            int och = (w * 5 + i) * 16 + l16;
            ah[i] = *(const bf16x8*)(wh + och * 256 + kc * 32 + quad * 8);
            al[i] = *(const bf16x8*)(wl + och * 256 + kc * 32 + quad * 8);
        }
        #pragma unroll
        for (int nt = 0; nt < 4; ++nt) {
            int roff = (nt * 16 + l16) * 512 + (((kc * 4 + quad) ^ (l16 & 7)) * 16);
            bf16x8 bh = *(const bf16x8*)(smem + roff);
            bf16x8 bl = *(const bf16x8*)(smem + PJ_XL + roff);
            #pragma unroll
            for (int i = 0; i < 5; ++i) {
                acc[i][nt] = MFMA16(ah[i], bh, acc[i][nt]);
                acc[i][nt] = MFMA16(al[i], bh, acc[i][nt]);
                acc[i][nt] = MFMA16(ah[i], bl, acc[i][nt]);
            }
        }
    }
    __syncthreads();

    #pragma unroll
    for (int i = 0; i < 5; ++i) {
        int tile = w * 5 + i;
        if (tile < 4) {
            #pragma unroll
            for (int r = 0; r < 4; ++r) {
                int och = tile * 16 + quad * 4 + r;
                float bias = (och < 32) ? bq[och] : bk[och - 32];
                int arr = (och < 32) ? 0 : 2;
                int oq = och & 31;
                #pragma unroll
                for (int nt = 0; nt < 4; ++nt) {
                    float val = acc[i][nt][r] + bias;
                    if (och < 32) val *= LOG2E;
                    unsigned short hi = f2bf(val);
                    unsigned short lo = f2bf(val - bf2f(hi));
                    *(unsigned short*)(smem + arr * 4096 + (nt * 16 + l16) * 64 + oq * 2) = hi;
                    *(unsigned short*)(smem + (arr + 1) * 4096 + (nt * 16 + l16) * 64 + oq * 2) = lo;
                }
            }
        } else {
            #pragma unroll
            for (int r = 0; r < 4; ++r) {
                int voch = tile * 16 + quad * 4 + r - 64;
                float bias = bv[voch];
                #pragma unroll
                for (int nt = 0; nt < 4; ++nt) {
                    *(unsigned short*)(smem + PJ_VE + voch * 136 + (nt * 16 + l16) * 2)
                        = f2bf(acc[i][nt][r] + bias);
                }
            }
        }
    }
    __syncthreads();

    {
        unsigned short* dsts[4] = { qh, ql, kh, kl };
        int arr = t >> 6, n = t & 63;
        unsigned short* dst = dsts[arr] + ((size_t)b * NN + n0 + n) * 32;
        #pragma unroll
        for (int i = 0; i < 4; ++i)
            *(us8*)(dst + i * 8) = *(const us8*)(smem + arr * 4096 + n * 64 + i * 16);
    }
    #pragma unroll
    for (int p = 0; p < 4; ++p) {
        int voch = p * 64 + (t >> 2), piece = t & 3;
        unsigned short* dst = vt + ((size_t)b * CH + voch) * NN + n0 + piece * 16;
        *(us8*)(dst)     = *(const us8*)(smem + PJ_VE + voch * 136 + piece * 32);
        *(us8*)(dst + 8) = *(const us8*)(smem + PJ_VE + voch * 136 + piece * 32 + 16);
    }
}

// ---------------------------------------------------------------------------
// Kernel 3: MFMA flash attention. Round-4 launch geometry (512 blocks x 256
// thr, b = blockIdx&7, 64 queries, full 4096-key sweep -- the PROVEN
// L2-resident stream, FETCH 12MB) + round-6 slim LDS body: V single 32KB +
// P single 8KB = 40KB -> 4 blocks/CU -> 4 waves/SIMD (2x round 4's TLP).
// Two barriers/tile: E -> A (P+V ready) -> Kpf + PV -> B -> V-stage(t+1).
// Single P is safe: E(t+1) writes only after B(t); PV(t) reads drain at B(t).
// Intra-block barrier stalls hidden by 3 other resident blocks per CU.
// ---------------------------------------------------------------------------
#define A_V  0          // V: 256ch x 128B = 32 KB
#define A_P  32768      // P: 64 rows x 128B = 8 KB (SM aliases post-loop)

__global__ __launch_bounds__(256, 4) void attn_kernel(
    const unsigned short* __restrict__ qh, const unsigned short* __restrict__ ql,
    const unsigned short* __restrict__ kh, const unsigned short* __restrict__ kl,
    const unsigned short* __restrict__ vt, const float* __restrict__ gptr,
    float* __restrict__ out)
{
    __shared__ __align__(16) unsigned char smem[40960];
    const int t    = threadIdx.x;
    const int lane = t & 63;
    const int w    = t >> 6;
    const int l16  = lane & 15;
    const int quad = lane >> 4;
    const int b    = blockIdx.x & 7;
    const int n0   = (blockIdx.x >> 3) << 6;

    // Q B-frags (hi/lo); Q pre-scaled by log2e
    bf16x8 qhA[4], qlA[4];
    #pragma unroll
    for (int qt = 0; qt < 4; ++qt) {
        size_t row = (size_t)b * NN + n0 + qt * 16 + l16;
        qhA[qt] = *(const bf16x8*)(qh + row * 32 + quad * 8);
        qlA[qt] = *(const bf16x8*)(ql + row * 32 + quad * 8);
    }

    // K A-frag base: wave w owns keys w*16..+15 of each 64-key tile
    const unsigned short* khbase = kh + ((size_t)b * NN + w * 16 + l16) * 32 + quad * 8;
    const unsigned short* klbase = kl + ((size_t)b * NN + w * 16 + l16) * 32 + quad * 8;
    const unsigned char*  vtB    = (const unsigned char*)(vt + (size_t)b * CH * NN);

    // hoisted V-stage offsets (256 rows x 128B per tile, chunk-XOR swizzle)
    unsigned int voff[8];
    #pragma unroll
    for (int j = 0; j < 8; ++j) {
        int idx = j * 256 + t;
        int r = idx >> 3, cl = idx & 7;
        int cg = cl ^ (r & 7);
        voff[j] = (unsigned int)(r * 8192 + cg * 16);
    }
    const unsigned char* vcur = vtB;   // advances 128 B per tile

    // P-write offset (lane-constant): row = query l16, key chunk XOR row&7
    const int poff = l16 * 128 + ((((w << 1) | (quad >> 1)) ^ (l16 & 7)) << 4)
                   + ((quad & 1) << 3);

    f32x4 acc[4][4] = {};
    float S[4] = {};

    // prologue: K(0) regs, then stage V(0)
    bf16x8 kch = *(const bf16x8*)(khbase);
    bf16x8 kcl = *(const bf16x8*)(klbase);
    #pragma unroll
    for (int j = 0; j < 8; ++j)
        gload16(vcur + voff[j], smem + A_V + (j * 256 + t) * 16);

    unsigned char* P = smem + A_P;
    #pragma unroll 1
    for (int tile = 0; tile < 64; ++tile) {
        // ---- E: swapped operands; lane holds 4 keys (quad*4+r) x query l16 ----
        #pragma unroll
        for (int qt = 0; qt < 4; ++qt) {
            f32x4 e = { 0.f, 0.f, 0.f, 0.f };
            e = MFMA16(kch, qhA[qt], e);
            e = MFMA16(kch, qlA[qt], e);
            e = MFMA16(kcl, qhA[qt], e);
            float p0 = exp2f(e[0]), p1 = exp2f(e[1]);
            float p2 = exp2f(e[2]), p3 = exp2f(e[3]);
            unsigned int u01, u23;
            asm("v_cvt_pk_bf16_f32 %0, %1, %2" : "=v"(u01) : "v"(p0), "v"(p1));
            asm("v_cvt_pk_bf16_f32 %0, %1, %2" : "=v"(u23) : "v"(p2), "v"(p3));
            // S sums the rounded values actually stored in P
            S[qt] += (__uint_as_float(u01 << 16) + __uint_as_float(u01 & 0xffff0000u))
                   + (__uint_as_float(u23 << 16) + __uint_as_float(u23 & 0xffff0000u));
            int2 pk2 = { (int)u01, (int)u23 };
            *(int2*)(P + qt * 2048 + poff) = pk2;
        }

        __syncthreads();   // A: P(t) visible to all waves; V(t) stage drained

        // ---- K(t+1) prefetch (regs; latency covered by PV) ----
        const int m1 = ((tile + 1) & 63) * 64;
        bf16x8 knh = *(const bf16x8*)(khbase + (size_t)m1 * 32);
        bf16x8 knl = *(const bf16x8*)(klbase + (size_t)m1 * 32);

        // ---- PV: A = P rows (queries), B = V rows (wave's 64 channels) ----
        #pragma unroll
        for (int ks = 0; ks < 2; ++ks) {
            bf16x8 af[4], bfr[4];
            #pragma unroll
            for (int qt = 0; qt < 4; ++qt) {
                int row = qt * 16 + l16;
                af[qt] = *(const bf16x8*)(P + row * 128
                                            + (((ks * 4 + quad) ^ (l16 & 7)) << 4));
            }
            #pragma unroll
            for (int ct = 0; ct < 4; ++ct) {
                int vrow = w * 64 + ct * 16 + l16;
                bfr[ct] = *(const bf16x8*)(smem + A_V + vrow * 128
                                              + (((ks * 4 + quad) ^ (l16 & 7)) << 4));
            }
            __builtin_amdgcn_s_setprio(1);
            #pragma unroll
            for (int qt = 0; qt < 4; ++qt)
                #pragma unroll
                for (int ct = 0; ct < 4; ++ct)
                    acc[qt][ct] = MFMA16(af[qt], bfr[ct], acc[qt][ct]);
            __builtin_amdgcn_s_setprio(0);
        }

        __syncthreads();   // B: all PV reads of P and V done

        // ---- issue V-stage(t+1) into the single V buffer ----
        if (tile < 63) {
            vcur += 128;
            #pragma unroll
            for (int j = 0; j < 8; ++j)
                gload16(vcur + voff[j], smem + A_V + (j * 256 + t) * 16);
        }
        kch = knh;
        kcl = knl;
    }

    // S: reduce over quads (same query in lanes l16+16q), then across waves
    #pragma unroll
    for (int mask = 16; mask <= 32; mask <<= 1)
        #pragma unroll
        for (int qt = 0; qt < 4; ++qt)
            S[qt] += __shfl_xor(S[qt], mask);
    float* SM = (float*)(smem + A_P);   // P dead after loop (B drained reads)
    if (quad == 0) {
        #pragma unroll
        for (int qt = 0; qt < 4; ++qt)
            SM[w * 64 + qt * 16 + l16] = S[qt];
    }
    __syncthreads();

    const float g1 = 1.f + gptr[0];
    float* ob = out + (size_t)b * CH * NN;
    #pragma unroll
    for (int qt = 0; qt < 4; ++qt) {
        float is[4];
        #pragma unroll
        for (int r = 0; r < 4; ++r) {
            int qi = qt * 16 + quad * 4 + r;
            float Sf = SM[qi] + SM[64 + qi] + SM[128 + qi] + SM[192 + qi];
            is[r] = g1 / Sf;
        }
        #pragma unroll
        for (int ct = 0; ct < 4; ++ct) {
            float4 o4;
            o4.x = floorf(acc[qt][ct][0] * is[0] * 256.f) * 0.00390625f;
            o4.y = floorf(acc[qt][ct][1] * is[1] * 256.f) * 0.00390625f;
            o4.z = floorf(acc[qt][ct][2] * is[2] * 256.f) * 0.00390625f;
            o4.w = floorf(acc[qt][ct][3] * is[3] * 256.f) * 0.00390625f;
            *(float4*)(ob + (size_t)(w * 64 + ct * 16 + l16) * NN
                          + n0 + qt * 16 + quad * 4) = o4;
        }
    }
}

// ---------------------------------------------------------------------------
extern "C" void kernel_launch(void* const* d_in, const int* in_sizes, int n_in,
                              void* d_out, int out_size, void* d_ws, size_t ws_size,
                              hipStream_t stream) {
    const float* x  = (const float*)d_in[0];
    const float* wq = (const float*)d_in[1];
    const float* bq = (const float*)d_in[2];
    const float* wk = (const float*)d_in[3];
    const float* bk = (const float*)d_in[4];
    const float* wv = (const float*)d_in[5];
    const float* bv = (const float*)d_in[6];
    const float* gm = (const float*)d_in[7];
    float* out = (float*)d_out;

    unsigned short* ws = (unsigned short*)d_ws;
    const size_t XSZ = (size_t)BB * NN * 256;   // 8,388,608
    const size_t WSZ = 320 * 256;               // 81,920
    const size_t QSZ = (size_t)BB * NN * 32;    // 1,048,576
    unsigned short* xh = ws;
    unsigned short* xl = xh + XSZ;
    unsigned short* wh = xl + XSZ;
    unsigned short* wl = wh + WSZ;
    unsigned short* qh = wl + WSZ;
    unsigned short* ql = qh + QSZ;
    unsigned short* kh = ql + QSZ;
    unsigned short* kl = kh + QSZ;
    unsigned short* vt = kl + QSZ;

    wsplit_kernel<<<320, 256, 0, stream>>>(wq, wk, wv, wh, wl);
    transpose_kernel<<<2048, 256, 0, stream>>>(x, xh, xl);
    proj_kernel<<<512, 256, 0, stream>>>(xh, xl, wh, wl, bq, bk, bv,
                                         qh, ql, kh, kl, vt);
    attn_kernel<<<512, 256, 0, stream>>>(qh, ql, kh, kl, vt, gm, out);
}

// Round 10
// 238.510 us; speedup vs baseline: 2.2939x; 2.2939x over previous
//
#include <hip/hip_runtime.h>
#include <math.h>

namespace {
constexpr int BB = 8;
constexpr int CH = 256;
constexpr int CQ = 32;
constexpr int NN = 4096;
}

typedef float f32x4 __attribute__((ext_vector_type(4)));
typedef short bf16x8 __attribute__((ext_vector_type(8)));
typedef unsigned short us8 __attribute__((ext_vector_type(8)));

#define MFMA16(a, b, c) __builtin_amdgcn_mfma_f32_16x16x32_bf16(a, b, c, 0, 0, 0)
#define LOG2E 1.4426950408889634f

__device__ __forceinline__ unsigned short f2bf(float x) {
    unsigned int u = __float_as_uint(x);
    u += 0x7fffu + ((u >> 16) & 1u);
    return (unsigned short)(u >> 16);
}
__device__ __forceinline__ float bf2f(unsigned short h) {
    return __uint_as_float(((unsigned int)h) << 16);
}
__device__ __forceinline__ void gload16(const void* g, void* l) {
    __builtin_amdgcn_global_load_lds(
        (const __attribute__((address_space(1))) unsigned int*)g,
        (__attribute__((address_space(3))) unsigned int*)l, 16, 0, 0);
}

// ---------------------------------------------------------------------------
// Kernel 0: split W (wq|wk|wv concat, 320x256) into bf16 hi/lo.
// ---------------------------------------------------------------------------
__global__ __launch_bounds__(256) void wsplit_kernel(
    const float* __restrict__ wq, const float* __restrict__ wk,
    const float* __restrict__ wv,
    unsigned short* __restrict__ wh, unsigned short* __restrict__ wl)
{
    int idx = blockIdx.x * 256 + threadIdx.x;   // 0..81919
    float v;
    if (idx < 8192)       v = wq[idx];
    else if (idx < 16384) v = wk[idx - 8192];
    else                  v = wv[idx - 16384];
    unsigned short hi = f2bf(v);
    wh[idx] = hi;
    wl[idx] = f2bf(v - bf2f(hi));
}

// ---------------------------------------------------------------------------
// Kernel 1: transpose+split X [b][256c][4096n] fp32 -> Xh/Xl [b][n][256c] bf16.
// ---------------------------------------------------------------------------
__global__ __launch_bounds__(256) void transpose_kernel(
    const float* __restrict__ x,
    unsigned short* __restrict__ xh, unsigned short* __restrict__ xl)
{
    __shared__ float xf[64 * 68];                 // fp32 tile, padded rows
    __shared__ unsigned short hs[64 * 80];        // bf16 [n][64c] padded
    __shared__ unsigned short ls[64 * 80];
    const int t  = threadIdx.x;
    const int b  = blockIdx.x >> 8;
    const int tl = blockIdx.x & 255;
    const int c0 = (tl >> 6) * 64;
    const int n0 = (tl & 63) * 64;

    #pragma unroll
    for (int i = 0; i < 4; ++i) {
        int idx = i * 256 + t;
        int c = idx >> 4, nf = idx & 15;
        float4 v4 = *(const float4*)(x + ((size_t)(b * 256 + c0 + c)) * NN + n0 + nf * 4);
        *(float4*)(xf + c * 68 + nf * 4) = v4;
    }
    __syncthreads();

    const int n = t & 63;
    #pragma unroll
    for (int loop = 0; loop < 2; ++loop) {
        int chunk = (t >> 6) + 4 * loop;          // 0..7 (8 c's each)
        us8 h8, l8;
        #pragma unroll
        for (int j = 0; j < 8; ++j) {
            float v = xf[(chunk * 8 + j) * 68 + n];
            unsigned short hi = f2bf(v);
            h8[j] = hi;
            l8[j] = f2bf(v - bf2f(hi));
        }
        *(us8*)(hs + n * 80 + chunk * 8) = h8;
        *(us8*)(ls + n * 80 + chunk * 8) = l8;
    }
    __syncthreads();

    {
        int rn = t >> 2, piece = t & 3;
        size_t grow = ((size_t)(b * NN + n0 + rn)) * 256 + c0 + piece * 16;
        *(us8*)(xh + grow)     = *(const us8*)(hs + rn * 80 + piece * 16);
        *(us8*)(xh + grow + 8) = *(const us8*)(hs + rn * 80 + piece * 16 + 8);
        *(us8*)(xl + grow)     = *(const us8*)(ls + rn * 80 + piece * 16);
        *(us8*)(xl + grow + 8) = *(const us8*)(ls + rn * 80 + piece * 16 + 8);
    }
}

// ---------------------------------------------------------------------------
// Kernel 2: proj GEMM via MFMA (round-4 verbatim; Q pre-scaled by log2e).
// ---------------------------------------------------------------------------
#define PJ_XL 32768
#define PJ_VE 16384
__global__ __launch_bounds__(256, 2) void proj_kernel(
    const unsigned short* __restrict__ xh, const unsigned short* __restrict__ xl,
    const unsigned short* __restrict__ wh, const unsigned short* __restrict__ wl,
    const float* __restrict__ bq, const float* __restrict__ bk,
    const float* __restrict__ bv,
    unsigned short* __restrict__ qh, unsigned short* __restrict__ ql,
    unsigned short* __restrict__ kh, unsigned short* __restrict__ kl,
    unsigned short* __restrict__ vt)
{
    __shared__ __align__(16) unsigned char smem[65536];
    const int t    = threadIdx.x;
    const int lane = t & 63;
    const int w    = t >> 6;
    const int l16  = lane & 15;
    const int quad = lane >> 4;
    const int b    = blockIdx.x >> 6;
    const int n0   = (blockIdx.x & 63) << 6;

    const unsigned char* xhB = (const unsigned char*)(xh + ((size_t)b * NN + n0) * 256);
    const unsigned char* xlB = (const unsigned char*)(xl + ((size_t)b * NN + n0) * 256);
    #pragma unroll
    for (int j = 0; j < 8; ++j) {
        int idx = j * 256 + t;
        int r = idx >> 5, cl = idx & 31;
        int cg = cl ^ (r & 7);
        gload16(xhB + (size_t)r * 512 + cg * 16, smem + idx * 16);
        gload16(xlB + (size_t)r * 512 + cg * 16, smem + PJ_XL + idx * 16);
    }
    __syncthreads();

    f32x4 acc[5][4] = {};
    #pragma unroll 1
    for (int kc = 0; kc < 8; ++kc) {
        bf16x8 ah[5], al[5];
        #pragma unroll
        for (int i = 0; i < 5; ++i) {
            int och = (w * 5 + i) * 16 + l16;
            ah[i] = *(const bf16x8*)(wh + och * 256 + kc * 32 + quad * 8);
            al[i] = *(const bf16x8*)(wl + och * 256 + kc * 32 + quad * 8);
        }
        #pragma unroll
        for (int nt = 0; nt < 4; ++nt) {
            int roff = (nt * 16 + l16) * 512 + (((kc * 4 + quad) ^ (l16 & 7)) * 16);
            bf16x8 bh = *(const bf16x8*)(smem + roff);
            bf16x8 bl = *(const bf16x8*)(smem + PJ_XL + roff);
            #pragma unroll
            for (int i = 0; i < 5; ++i) {
                acc[i][nt] = MFMA16(ah[i], bh, acc[i][nt]);
                acc[i][nt] = MFMA16(al[i], bh, acc[i][nt]);
                acc[i][nt] = MFMA16(ah[i], bl, acc[i][nt]);
            }
        }
    }
    __syncthreads();

    #pragma unroll
    for (int i = 0; i < 5; ++i) {
        int tile = w * 5 + i;
        if (tile < 4) {
            #pragma unroll
            for (int r = 0; r < 4; ++r) {
                int och = tile * 16 + quad * 4 + r;
                float bias = (och < 32) ? bq[och] : bk[och - 32];
                int arr = (och < 32) ? 0 : 2;
                int oq = och & 31;
                #pragma unroll
                for (int nt = 0; nt < 4; ++nt) {
                    float val = acc[i][nt][r] + bias;
                    if (och < 32) val *= LOG2E;
                    unsigned short hi = f2bf(val);
                    unsigned short lo = f2bf(val - bf2f(hi));
                    *(unsigned short*)(smem + arr * 4096 + (nt * 16 + l16) * 64 + oq * 2) = hi;
                    *(unsigned short*)(smem + (arr + 1) * 4096 + (nt * 16 + l16) * 64 + oq * 2) = lo;
                }
            }
        } else {
            #pragma unroll
            for (int r = 0; r < 4; ++r) {
                int voch = tile * 16 + quad * 4 + r - 64;
                float bias = bv[voch];
                #pragma unroll
                for (int nt = 0; nt < 4; ++nt) {
                    *(unsigned short*)(smem + PJ_VE + voch * 136 + (nt * 16 + l16) * 2)
                        = f2bf(acc[i][nt][r] + bias);
                }
            }
        }
    }
    __syncthreads();

    {
        unsigned short* dsts[4] = { qh, ql, kh, kl };
        int arr = t >> 6, n = t & 63;
        unsigned short* dst = dsts[arr] + ((size_t)b * NN + n0 + n) * 32;
        #pragma unroll
        for (int i = 0; i < 4; ++i)
            *(us8*)(dst + i * 8) = *(const us8*)(smem + arr * 4096 + n * 64 + i * 16);
    }
    #pragma unroll
    for (int p = 0; p < 4; ++p) {
        int voch = p * 64 + (t >> 2), piece = t & 3;
        unsigned short* dst = vt + ((size_t)b * CH + voch) * NN + n0 + piece * 16;
        *(us8*)(dst)     = *(const us8*)(smem + PJ_VE + voch * 136 + piece * 32);
        *(us8*)(dst + 8) = *(const us8*)(smem + PJ_VE + voch * 136 + piece * 32 + 16);
    }
}

// ---------------------------------------------------------------------------
// Kernel 3: MFMA flash attention -- ROUND-4 CONFIG VERBATIM (512 blocks x
// 256 thr, b=blockIdx&7, 80KB LDS, V dbuf 2x32KB, P dbuf 2x8KB, ONE
// barrier/tile: the proven L2-resident stream, FETCH 12MB). In-config
// scheduling changes only:
//  - E: 12-MFMA setprio cluster first, THEN the exp/pack/S VALU cluster
//    (creates wave role diversity so co-resident waves interleave).
//  - PV: all 16 LDS reads hoisted ahead of a single 32-MFMA setprio
//    cluster (removes mid-phase ds_read bubble; all indices static).
// ---------------------------------------------------------------------------
#define A_P0 0          // P buffer 0: 64 rows x 128B
#define A_P1 8192       // P buffer 1
#define A_V0 16384      // V buffer 0: 256ch x 128B
#define A_V1 49152      // V buffer 1
#define A_SM 16384      // 256 floats, aliases V0 (post-loop only)

__global__ __launch_bounds__(256, 2) void attn_kernel(
    const unsigned short* __restrict__ qh, const unsigned short* __restrict__ ql,
    const unsigned short* __restrict__ kh, const unsigned short* __restrict__ kl,
    const unsigned short* __restrict__ vt, const float* __restrict__ gptr,
    float* __restrict__ out)
{
    __shared__ __align__(16) unsigned char smem[81920];
    const int t    = threadIdx.x;
    const int lane = t & 63;
    const int w    = t >> 6;
    const int l16  = lane & 15;
    const int quad = lane >> 4;
    const int b    = blockIdx.x & 7;
    const int n0   = (blockIdx.x >> 3) << 6;

    // Q B-frags (hi/lo); Q pre-scaled by log2e
    bf16x8 qhA[4], qlA[4];
    #pragma unroll
    for (int qt = 0; qt < 4; ++qt) {
        size_t row = (size_t)b * NN + n0 + qt * 16 + l16;
        qhA[qt] = *(const bf16x8*)(qh + row * 32 + quad * 8);
        qlA[qt] = *(const bf16x8*)(ql + row * 32 + quad * 8);
    }

    // K A-frag base: wave w owns keys w*16..+15 of each 64-key tile
    const unsigned short* khbase = kh + ((size_t)b * NN + w * 16 + l16) * 32 + quad * 8;
    const unsigned short* klbase = kl + ((size_t)b * NN + w * 16 + l16) * 32 + quad * 8;
    const unsigned char*  vtB    = (const unsigned char*)(vt + (size_t)b * CH * NN);

    // hoisted per-thread stage addresses
    const unsigned char* vsrc[8];
    int vlds[8];
    #pragma unroll
    for (int j = 0; j < 8; ++j) {
        int idx = j * 256 + t;
        int r = idx >> 3, cl = idx & 7;
        int cg = cl ^ (r & 7);
        vsrc[j] = vtB + (size_t)r * 8192 + cg * 16;   // tile-0 base
        vlds[j] = idx * 16;
    }
    // P-write offset (lane-constant): row = query l16, key chunk XOR row&7
    const int poff = l16 * 128 + ((((w << 1) | (quad >> 1)) ^ (l16 & 7)) << 4)
                   + ((quad & 1) << 3);

    f32x4 acc[4][4] = {};
    float S[4] = {};

    // prologue: K(0) regs first, then stage V(0) into V0
    bf16x8 kch = *(const bf16x8*)(khbase);
    bf16x8 kcl = *(const bf16x8*)(klbase);
    #pragma unroll
    for (int j = 0; j < 8; ++j)
        gload16(vsrc[j], smem + A_V0 + vlds[j]);

    #pragma unroll 1
    for (int tile = 0; tile < 64; ++tile) {
        unsigned char* P = smem + ((tile & 1) ? A_P1 : A_P0);

        // ---- E, MFMA cluster: all 12 MFMAs back-to-back ----
        f32x4 e4[4];
        __builtin_amdgcn_s_setprio(1);
        #pragma unroll
        for (int qt = 0; qt < 4; ++qt) {
            f32x4 e = { 0.f, 0.f, 0.f, 0.f };
            e = MFMA16(kch, qhA[qt], e);
            e = MFMA16(kch, qlA[qt], e);
            e = MFMA16(kcl, qhA[qt], e);
            e4[qt] = e;
        }
        __builtin_amdgcn_s_setprio(0);

        // ---- E, VALU cluster: exp2 / pack / S / P-write ----
        #pragma unroll
        for (int qt = 0; qt < 4; ++qt) {
            float p0 = exp2f(e4[qt][0]), p1 = exp2f(e4[qt][1]);
            float p2 = exp2f(e4[qt][2]), p3 = exp2f(e4[qt][3]);
            unsigned int u01, u23;
            asm("v_cvt_pk_bf16_f32 %0, %1, %2" : "=v"(u01) : "v"(p0), "v"(p1));
            asm("v_cvt_pk_bf16_f32 %0, %1, %2" : "=v"(u23) : "v"(p2), "v"(p3));
            // S sums the rounded values actually stored in P
            S[qt] += (__uint_as_float(u01 << 16) + __uint_as_float(u01 & 0xffff0000u))
                   + (__uint_as_float(u23 << 16) + __uint_as_float(u23 & 0xffff0000u));
            int2 pk2 = { (int)u01, (int)u23 };
            *(int2*)(P + qt * 2048 + poff) = pk2;
        }

        __syncthreads();   // P(tile) + V(tile) ready; prev PV reads drained

        // ---- post-barrier VMEM issue (consumed after NEXT barrier) ----
        const int m1 = ((tile + 1) & 63) * 64;
        bf16x8 knh = *(const bf16x8*)(khbase + (size_t)m1 * 32);
        bf16x8 knl = *(const bf16x8*)(klbase + (size_t)m1 * 32);
        if (tile < 63) {
            unsigned char* vdst = smem + ((tile & 1) ? A_V0 : A_V1);
            #pragma unroll
            for (int j = 0; j < 8; ++j) {
                vsrc[j] += 128;
                gload16(vsrc[j], vdst + vlds[j]);
            }
        }

        // ---- PV: hoist ALL 16 LDS reads, then one 32-MFMA cluster ----
        const unsigned char* VB = smem + ((tile & 1) ? A_V1 : A_V0);
        bf16x8 af0[4], af1[4], bf0[4], bf1[4];
        #pragma unroll
        for (int qt = 0; qt < 4; ++qt) {
            int row = qt * 16 + l16;
            af0[qt] = *(const bf16x8*)(P + row * 128
                                         + (((0 * 4 + quad) ^ (l16 & 7)) << 4));
            af1[qt] = *(const bf16x8*)(P + row * 128
                                         + (((1 * 4 + quad) ^ (l16 & 7)) << 4));
        }
        #pragma unroll
        for (int ct = 0; ct < 4; ++ct) {
            int vrow = w * 64 + ct * 16 + l16;
            bf0[ct] = *(const bf16x8*)(VB + vrow * 128
                                          + (((0 * 4 + quad) ^ (l16 & 7)) << 4));
            bf1[ct] = *(const bf16x8*)(VB + vrow * 128
                                          + (((1 * 4 + quad) ^ (l16 & 7)) << 4));
        }
        __builtin_amdgcn_s_setprio(1);
        #pragma unroll
        for (int qt = 0; qt < 4; ++qt)
            #pragma unroll
            for (int ct = 0; ct < 4; ++ct)
                acc[qt][ct] = MFMA16(af0[qt], bf0[ct], acc[qt][ct]);
        #pragma unroll
        for (int qt = 0; qt < 4; ++qt)
            #pragma unroll
            for (int ct = 0; ct < 4; ++ct)
                acc[qt][ct] = MFMA16(af1[qt], bf1[ct], acc[qt][ct]);
        __builtin_amdgcn_s_setprio(0);

        kch = knh;
        kcl = knl;
    }

    // S: reduce over quads (same query in lanes l16+16q), then across waves
    #pragma unroll
    for (int mask = 16; mask <= 32; mask <<= 1)
        #pragma unroll
        for (int qt = 0; qt < 4; ++qt)
            S[qt] += __shfl_xor(S[qt], mask);
    float* SM = (float*)(smem + A_SM);
    if (quad == 0) {
        #pragma unroll
        for (int qt = 0; qt < 4; ++qt)
            SM[w * 64 + qt * 16 + l16] = S[qt];
    }
    __syncthreads();

    const float g1 = 1.f + gptr[0];
    float* ob = out + (size_t)b * CH * NN;
    #pragma unroll
    for (int qt = 0; qt < 4; ++qt) {
        float is[4];
        #pragma unroll
        for (int r = 0; r < 4; ++r) {
            int qi = qt * 16 + quad * 4 + r;
            float Sf = SM[qi] + SM[64 + qi] + SM[128 + qi] + SM[192 + qi];
            is[r] = g1 / Sf;
        }
        #pragma unroll
        for (int ct = 0; ct < 4; ++ct) {
            float4 o4;
            o4.x = floorf(acc[qt][ct][0] * is[0] * 256.f) * 0.00390625f;
            o4.y = floorf(acc[qt][ct][1] * is[1] * 256.f) * 0.00390625f;
            o4.z = floorf(acc[qt][ct][2] * is[2] * 256.f) * 0.00390625f;
            o4.w = floorf(acc[qt][ct][3] * is[3] * 256.f) * 0.00390625f;
            *(float4*)(ob + (size_t)(w * 64 + ct * 16 + l16) * NN
                          + n0 + qt * 16 + quad * 4) = o4;
        }
    }
}

// ---------------------------------------------------------------------------
extern "C" void kernel_launch(void* const* d_in, const int* in_sizes, int n_in,
                              void* d_out, int out_size, void* d_ws, size_t ws_size,
                              hipStream_t stream) {
    const float* x  = (const float*)d_in[0];
    const float* wq = (const float*)d_in[1];
    const float* bq = (const float*)d_in[2];
    const float* wk = (const float*)d_in[3];
    const float* bk = (const float*)d_in[4];
    const float* wv = (const float*)d_in[5];
    const float* bv = (const float*)d_in[6];
    const float* gm = (const float*)d_in[7];
    float* out = (float*)d_out;

    unsigned short* ws = (unsigned short*)d_ws;
    const size_t XSZ = (size_t)BB * NN * 256;   // 8,388,608
    const size_t WSZ = 320 * 256;               // 81,920
    const size_t QSZ = (size_t)BB * NN * 32;    // 1,048,576
    unsigned short* xh = ws;
    unsigned short* xl = xh + XSZ;
    unsigned short* wh = xl + XSZ;
    unsigned short* wl = wh + WSZ;
    unsigned short* qh = wl + WSZ;
    unsigned short* ql = qh + QSZ;
    unsigned short* kh = ql + QSZ;
    unsigned short* kl = kh + QSZ;
    unsigned short* vt = kl + QSZ;

    wsplit_kernel<<<320, 256, 0, stream>>>(wq, wk, wv, wh, wl);
    transpose_kernel<<<2048, 256, 0, stream>>>(x, xh, xl);
    proj_kernel<<<512, 256, 0, stream>>>(xh, xl, wh, wl, bq, bk, bv,
                                         qh, ql, kh, kl, vt);
    attn_kernel<<<512, 256, 0, stream>>>(qh, ql, kh, kl, vt, gm, out);
}

// Round 11
// 227.324 us; speedup vs baseline: 2.4068x; 1.0492x over previous
//
#include <hip/hip_runtime.h>
#include <math.h>

namespace {
constexpr int BB = 8;
constexpr int CH = 256;
constexpr int CQ = 32;
constexpr int NN = 4096;
}

typedef float f32x4 __attribute__((ext_vector_type(4)));
typedef short bf16x8 __attribute__((ext_vector_type(8)));
typedef unsigned short us8 __attribute__((ext_vector_type(8)));

#define MFMA16(a, b, c) __builtin_amdgcn_mfma_f32_16x16x32_bf16(a, b, c, 0, 0, 0)
#define LOG2E 1.4426950408889634f

__device__ __forceinline__ unsigned short f2bf(float x) {
    unsigned int u = __float_as_uint(x);
    u += 0x7fffu + ((u >> 16) & 1u);
    return (unsigned short)(u >> 16);
}
__device__ __forceinline__ float bf2f(unsigned short h) {
    return __uint_as_float(((unsigned int)h) << 16);
}
__device__ __forceinline__ void gload16(const void* g, void* l) {
    __builtin_amdgcn_global_load_lds(
        (const __attribute__((address_space(1))) unsigned int*)g,
        (__attribute__((address_space(3))) unsigned int*)l, 16, 0, 0);
}

// ---------------------------------------------------------------------------
// Kernel 0: split W (wq|wk|wv concat, 320x256) into bf16 hi/lo.
// ---------------------------------------------------------------------------
__global__ __launch_bounds__(256) void wsplit_kernel(
    const float* __restrict__ wq, const float* __restrict__ wk,
    const float* __restrict__ wv,
    unsigned short* __restrict__ wh, unsigned short* __restrict__ wl)
{
    int idx = blockIdx.x * 256 + threadIdx.x;   // 0..81919
    float v;
    if (idx < 8192)       v = wq[idx];
    else if (idx < 16384) v = wk[idx - 8192];
    else                  v = wv[idx - 16384];
    unsigned short hi = f2bf(v);
    wh[idx] = hi;
    wl[idx] = f2bf(v - bf2f(hi));
}

// ---------------------------------------------------------------------------
// Kernel 1 (fused transpose+proj): stage x fp32 tile straight from global,
// convert to bf16 hi/lo in registers, write the SAME swizzled LDS layout the
// GEMM core consumed before ([64n][256c], row 512B, chunk^(n&7) XOR). This
// removes the xh/xl 64MB write + 32MB re-read and the whole transpose
// kernel. GEMM core, W path, epilogue: byte-identical to round 4.
// Per-wave global reads: 64 consecutive floats (256B) per (pass, j) -- every
// x element read exactly once chip-wide.
// ---------------------------------------------------------------------------
#define PJ_XL 32768
#define PJ_VE 16384
__global__ __launch_bounds__(256, 2) void proj_kernel(
    const float* __restrict__ x,
    const unsigned short* __restrict__ wh, const unsigned short* __restrict__ wl,
    const float* __restrict__ bq, const float* __restrict__ bk,
    const float* __restrict__ bv,
    unsigned short* __restrict__ qh, unsigned short* __restrict__ ql,
    unsigned short* __restrict__ kh, unsigned short* __restrict__ kl,
    unsigned short* __restrict__ vt)
{
    __shared__ __align__(16) unsigned char smem[65536];
    const int t    = threadIdx.x;
    const int lane = t & 63;
    const int w    = t >> 6;
    const int l16  = lane & 15;
    const int quad = lane >> 4;
    const int b    = blockIdx.x >> 6;
    const int n0   = (blockIdx.x & 63) << 6;

    // ---- staging: global fp32 -> regs -> bf16 hi/lo -> swizzled LDS ----
    {
        const float* xB = x + (size_t)b * 256 * NN + n0;
        const int n = lane;            // pixel row 0..63
        #pragma unroll 2
        for (int p = 0; p < 8; ++p) {
            int cc = p * 4 + w;        // 16B chunk index 0..31 (8 channels)
            float v[8];
            #pragma unroll
            for (int j = 0; j < 8; ++j)
                v[j] = xB[(size_t)(cc * 8 + j) * NN + n];
            us8 h8, l8;
            #pragma unroll
            for (int j = 0; j < 8; ++j) {
                unsigned short hi = f2bf(v[j]);
                h8[j] = hi;
                l8[j] = f2bf(v[j] - bf2f(hi));
            }
            int off = n * 512 + ((cc ^ (n & 7)) << 4);
            *(us8*)(smem + off) = h8;
            *(us8*)(smem + PJ_XL + off) = l8;
        }
    }
    __syncthreads();

    f32x4 acc[5][4] = {};
    #pragma unroll 1
    for (int kc = 0; kc < 8; ++kc) {
        bf16x8 ah[5], al[5];
        #pragma unroll
        for (int i = 0; i < 5; ++i) {
            int och = (w * 5 + i) * 16 + l16;
            ah[i] = *(const bf16x8*)(wh + och * 256 + kc * 32 + quad * 8);
            al[i] = *(const bf16x8*)(wl + och * 256 + kc * 32 + quad * 8);
        }
        #pragma unroll
        for (int nt = 0; nt < 4; ++nt) {
            int roff = (nt * 16 + l16) * 512 + (((kc * 4 + quad) ^ (l16 & 7)) * 16);
            bf16x8 bh = *(const bf16x8*)(smem + roff);
            bf16x8 bl = *(const bf16x8*)(smem + PJ_XL + roff);
            #pragma unroll
            for (int i = 0; i < 5; ++i) {
                acc[i][nt] = MFMA16(ah[i], bh, acc[i][nt]);
                acc[i][nt] = MFMA16(al[i], bh, acc[i][nt]);
                acc[i][nt] = MFMA16(ah[i], bl, acc[i][nt]);
            }
        }
    }
    __syncthreads();

    #pragma unroll
    for (int i = 0; i < 5; ++i) {
        int tile = w * 5 + i;
        if (tile < 4) {
            #pragma unroll
            for (int r = 0; r < 4; ++r) {
                int och = tile * 16 + quad * 4 + r;
                float bias = (och < 32) ? bq[och] : bk[och - 32];
                int arr = (och < 32) ? 0 : 2;
                int oq = och & 31;
                #pragma unroll
                for (int nt = 0; nt < 4; ++nt) {
                    float val = acc[i][nt][r] + bias;
                    if (och < 32) val *= LOG2E;
                    unsigned short hi = f2bf(val);
                    unsigned short lo = f2bf(val - bf2f(hi));
                    *(unsigned short*)(smem + arr * 4096 + (nt * 16 + l16) * 64 + oq * 2) = hi;
                    *(unsigned short*)(smem + (arr + 1) * 4096 + (nt * 16 + l16) * 64 + oq * 2) = lo;
                }
            }
        } else {
            #pragma unroll
            for (int r = 0; r < 4; ++r) {
                int voch = tile * 16 + quad * 4 + r - 64;
                float bias = bv[voch];
                #pragma unroll
                for (int nt = 0; nt < 4; ++nt) {
                    *(unsigned short*)(smem + PJ_VE + voch * 136 + (nt * 16 + l16) * 2)
                        = f2bf(acc[i][nt][r] + bias);
                }
            }
        }
    }
    __syncthreads();

    {
        unsigned short* dsts[4] = { qh, ql, kh, kl };
        int arr = t >> 6, n = t & 63;
        unsigned short* dst = dsts[arr] + ((size_t)b * NN + n0 + n) * 32;
        #pragma unroll
        for (int i = 0; i < 4; ++i)
            *(us8*)(dst + i * 8) = *(const us8*)(smem + arr * 4096 + n * 64 + i * 16);
    }
    #pragma unroll
    for (int p = 0; p < 4; ++p) {
        int voch = p * 64 + (t >> 2), piece = t & 3;
        unsigned short* dst = vt + ((size_t)b * CH + voch) * NN + n0 + piece * 16;
        *(us8*)(dst)     = *(const us8*)(smem + PJ_VE + voch * 136 + piece * 32);
        *(us8*)(dst + 8) = *(const us8*)(smem + PJ_VE + voch * 136 + piece * 32 + 16);
    }
}

// ---------------------------------------------------------------------------
// Kernel 3: MFMA flash attention -- ROUND-10 VERBATIM (proven 122.5us,
// FETCH 12.3MB): 512 blocks x 256 thr, b=blockIdx&7, 80KB LDS, V dbuf
// 2x32KB, P dbuf 2x8KB, ONE barrier/tile; E 12-MFMA setprio cluster then
// VALU cluster; PV 16 hoisted LDS reads then one 32-MFMA setprio cluster.
// ---------------------------------------------------------------------------
#define A_P0 0          // P buffer 0: 64 rows x 128B
#define A_P1 8192       // P buffer 1
#define A_V0 16384      // V buffer 0: 256ch x 128B
#define A_V1 49152      // V buffer 1
#define A_SM 16384      // 256 floats, aliases V0 (post-loop only)

__global__ __launch_bounds__(256, 2) void attn_kernel(
    const unsigned short* __restrict__ qh, const unsigned short* __restrict__ ql,
    const unsigned short* __restrict__ kh, const unsigned short* __restrict__ kl,
    const unsigned short* __restrict__ vt, const float* __restrict__ gptr,
    float* __restrict__ out)
{
    __shared__ __align__(16) unsigned char smem[81920];
    const int t    = threadIdx.x;
    const int lane = t & 63;
    const int w    = t >> 6;
    const int l16  = lane & 15;
    const int quad = lane >> 4;
    const int b    = blockIdx.x & 7;
    const int n0   = (blockIdx.x >> 3) << 6;

    // Q B-frags (hi/lo); Q pre-scaled by log2e
    bf16x8 qhA[4], qlA[4];
    #pragma unroll
    for (int qt = 0; qt < 4; ++qt) {
        size_t row = (size_t)b * NN + n0 + qt * 16 + l16;
        qhA[qt] = *(const bf16x8*)(qh + row * 32 + quad * 8);
        qlA[qt] = *(const bf16x8*)(ql + row * 32 + quad * 8);
    }

    // K A-frag base: wave w owns keys w*16..+15 of each 64-key tile
    const unsigned short* khbase = kh + ((size_t)b * NN + w * 16 + l16) * 32 + quad * 8;
    const unsigned short* klbase = kl + ((size_t)b * NN + w * 16 + l16) * 32 + quad * 8;
    const unsigned char*  vtB    = (const unsigned char*)(vt + (size_t)b * CH * NN);

    // hoisted per-thread stage addresses
    const unsigned char* vsrc[8];
    int vlds[8];
    #pragma unroll
    for (int j = 0; j < 8; ++j) {
        int idx = j * 256 + t;
        int r = idx >> 3, cl = idx & 7;
        int cg = cl ^ (r & 7);
        vsrc[j] = vtB + (size_t)r * 8192 + cg * 16;   // tile-0 base
        vlds[j] = idx * 16;
    }
    // P-write offset (lane-constant): row = query l16, key chunk XOR row&7
    const int poff = l16 * 128 + ((((w << 1) | (quad >> 1)) ^ (l16 & 7)) << 4)
                   + ((quad & 1) << 3);

    f32x4 acc[4][4] = {};
    float S[4] = {};

    // prologue: K(0) regs first, then stage V(0) into V0
    bf16x8 kch = *(const bf16x8*)(khbase);
    bf16x8 kcl = *(const bf16x8*)(klbase);
    #pragma unroll
    for (int j = 0; j < 8; ++j)
        gload16(vsrc[j], smem + A_V0 + vlds[j]);

    #pragma unroll 1
    for (int tile = 0; tile < 64; ++tile) {
        unsigned char* P = smem + ((tile & 1) ? A_P1 : A_P0);

        // ---- E, MFMA cluster: all 12 MFMAs back-to-back ----
        f32x4 e4[4];
        __builtin_amdgcn_s_setprio(1);
        #pragma unroll
        for (int qt = 0; qt < 4; ++qt) {
            f32x4 e = { 0.f, 0.f, 0.f, 0.f };
            e = MFMA16(kch, qhA[qt], e);
            e = MFMA16(kch, qlA[qt], e);
            e = MFMA16(kcl, qhA[qt], e);
            e4[qt] = e;
        }
        __builtin_amdgcn_s_setprio(0);

        // ---- E, VALU cluster: exp2 / pack / S / P-write ----
        #pragma unroll
        for (int qt = 0; qt < 4; ++qt) {
            float p0 = exp2f(e4[qt][0]), p1 = exp2f(e4[qt][1]);
            float p2 = exp2f(e4[qt][2]), p3 = exp2f(e4[qt][3]);
            unsigned int u01, u23;
            asm("v_cvt_pk_bf16_f32 %0, %1, %2" : "=v"(u01) : "v"(p0), "v"(p1));
            asm("v_cvt_pk_bf16_f32 %0, %1, %2" : "=v"(u23) : "v"(p2), "v"(p3));
            // S sums the rounded values actually stored in P
            S[qt] += (__uint_as_float(u01 << 16) + __uint_as_float(u01 & 0xffff0000u))
                   + (__uint_as_float(u23 << 16) + __uint_as_float(u23 & 0xffff0000u));
            int2 pk2 = { (int)u01, (int)u23 };
            *(int2*)(P + qt * 2048 + poff) = pk2;
        }

        __syncthreads();   // P(tile) + V(tile) ready; prev PV reads drained

        // ---- post-barrier VMEM issue (consumed after NEXT barrier) ----
        const int m1 = ((tile + 1) & 63) * 64;
        bf16x8 knh = *(const bf16x8*)(khbase + (size_t)m1 * 32);
        bf16x8 knl = *(const bf16x8*)(klbase + (size_t)m1 * 32);
        if (tile < 63) {
            unsigned char* vdst = smem + ((tile & 1) ? A_V0 : A_V1);
            #pragma unroll
            for (int j = 0; j < 8; ++j) {
                vsrc[j] += 128;
                gload16(vsrc[j], vdst + vlds[j]);
            }
        }

        // ---- PV: hoist ALL 16 LDS reads, then one 32-MFMA cluster ----
        const unsigned char* VB = smem + ((tile & 1) ? A_V1 : A_V0);
        bf16x8 af0[4], af1[4], bf0[4], bf1[4];
        #pragma unroll
        for (int qt = 0; qt < 4; ++qt) {
            int row = qt * 16 + l16;
            af0[qt] = *(const bf16x8*)(P + row * 128
                                         + (((0 * 4 + quad) ^ (l16 & 7)) << 4));
            af1[qt] = *(const bf16x8*)(P + row * 128
                                         + (((1 * 4 + quad) ^ (l16 & 7)) << 4));
        }
        #pragma unroll
        for (int ct = 0; ct < 4; ++ct) {
            int vrow = w * 64 + ct * 16 + l16;
            bf0[ct] = *(const bf16x8*)(VB + vrow * 128
                                          + (((0 * 4 + quad) ^ (l16 & 7)) << 4));
            bf1[ct] = *(const bf16x8*)(VB + vrow * 128
                                          + (((1 * 4 + quad) ^ (l16 & 7)) << 4));
        }
        __builtin_amdgcn_s_setprio(1);
        #pragma unroll
        for (int qt = 0; qt < 4; ++qt)
            #pragma unroll
            for (int ct = 0; ct < 4; ++ct)
                acc[qt][ct] = MFMA16(af0[qt], bf0[ct], acc[qt][ct]);
        #pragma unroll
        for (int qt = 0; qt < 4; ++qt)
            #pragma unroll
            for (int ct = 0; ct < 4; ++ct)
                acc[qt][ct] = MFMA16(af1[qt], bf1[ct], acc[qt][ct]);
        __builtin_amdgcn_s_setprio(0);

        kch = knh;
        kcl = knl;
    }

    // S: reduce over quads (same query in lanes l16+16q), then across waves
    #pragma unroll
    for (int mask = 16; mask <= 32; mask <<= 1)
        #pragma unroll
        for (int qt = 0; qt < 4; ++qt)
            S[qt] += __shfl_xor(S[qt], mask);
    float* SM = (float*)(smem + A_SM);
    if (quad == 0) {
        #pragma unroll
        for (int qt = 0; qt < 4; ++qt)
            SM[w * 64 + qt * 16 + l16] = S[qt];
    }
    __syncthreads();

    const float g1 = 1.f + gptr[0];
    float* ob = out + (size_t)b * CH * NN;
    #pragma unroll
    for (int qt = 0; qt < 4; ++qt) {
        float is[4];
        #pragma unroll
        for (int r = 0; r < 4; ++r) {
            int qi = qt * 16 + quad * 4 + r;
            float Sf = SM[qi] + SM[64 + qi] + SM[128 + qi] + SM[192 + qi];
            is[r] = g1 / Sf;
        }
        #pragma unroll
        for (int ct = 0; ct < 4; ++ct) {
            float4 o4;
            o4.x = floorf(acc[qt][ct][0] * is[0] * 256.f) * 0.00390625f;
            o4.y = floorf(acc[qt][ct][1] * is[1] * 256.f) * 0.00390625f;
            o4.z = floorf(acc[qt][ct][2] * is[2] * 256.f) * 0.00390625f;
            o4.w = floorf(acc[qt][ct][3] * is[3] * 256.f) * 0.00390625f;
            *(float4*)(ob + (size_t)(w * 64 + ct * 16 + l16) * NN
                          + n0 + qt * 16 + quad * 4) = o4;
        }
    }
}

// ---------------------------------------------------------------------------
extern "C" void kernel_launch(void* const* d_in, const int* in_sizes, int n_in,
                              void* d_out, int out_size, void* d_ws, size_t ws_size,
                              hipStream_t stream) {
    const float* x  = (const float*)d_in[0];
    const float* wq = (const float*)d_in[1];
    const float* bq = (const float*)d_in[2];
    const float* wk = (const float*)d_in[3];
    const float* bk = (const float*)d_in[4];
    const float* wv = (const float*)d_in[5];
    const float* bv = (const float*)d_in[6];
    const float* gm = (const float*)d_in[7];
    float* out = (float*)d_out;

    unsigned short* ws = (unsigned short*)d_ws;
    const size_t WSZ = 320 * 256;               // 81,920
    const size_t QSZ = (size_t)BB * NN * 32;    // 1,048,576
    const size_t XSZ = (size_t)BB * NN * 256;   // 8,388,608
    unsigned short* wh = ws;
    unsigned short* wl = wh + WSZ;
    unsigned short* qh = wl + WSZ;
    unsigned short* ql = qh + QSZ;
    unsigned short* kh = ql + QSZ;
    unsigned short* kl = kh + QSZ;
    unsigned short* vt = kl + QSZ;              // vt size XSZ

    wsplit_kernel<<<320, 256, 0, stream>>>(wq, wk, wv, wh, wl);
    proj_kernel<<<512, 256, 0, stream>>>(x, wh, wl, bq, bk, bv,
                                         qh, ql, kh, kl, vt);
    attn_kernel<<<512, 256, 0, stream>>>(qh, ql, kh, kl, vt, gm, out);
}

// Round 12
// 223.571 us; speedup vs baseline: 2.4471x; 1.0168x over previous
//
#include <hip/hip_runtime.h>
#include <math.h>

namespace {
constexpr int BB = 8;
constexpr int CH = 256;
constexpr int CQ = 32;
constexpr int NN = 4096;
}

typedef float f32x4 __attribute__((ext_vector_type(4)));
typedef short bf16x8 __attribute__((ext_vector_type(8)));
typedef unsigned short us8 __attribute__((ext_vector_type(8)));

#define MFMA16(a, b, c) __builtin_amdgcn_mfma_f32_16x16x32_bf16(a, b, c, 0, 0, 0)
#define LOG2E 1.4426950408889634f

__device__ __forceinline__ unsigned short f2bf(float x) {
    unsigned int u = __float_as_uint(x);
    u += 0x7fffu + ((u >> 16) & 1u);
    return (unsigned short)(u >> 16);
}
__device__ __forceinline__ float bf2f(unsigned short h) {
    return __uint_as_float(((unsigned int)h) << 16);
}
__device__ __forceinline__ void gload16(const void* g, void* l) {
    __builtin_amdgcn_global_load_lds(
        (const __attribute__((address_space(1))) unsigned int*)g,
        (__attribute__((address_space(3))) unsigned int*)l, 16, 0, 0);
}

// ---------------------------------------------------------------------------
// Kernel 0: split W (wq|wk|wv concat, 320x256) into bf16 hi/lo.
// ---------------------------------------------------------------------------
__global__ __launch_bounds__(256) void wsplit_kernel(
    const float* __restrict__ wq, const float* __restrict__ wk,
    const float* __restrict__ wv,
    unsigned short* __restrict__ wh, unsigned short* __restrict__ wl)
{
    int idx = blockIdx.x * 256 + threadIdx.x;   // 0..81919
    float v;
    if (idx < 8192)       v = wq[idx];
    else if (idx < 16384) v = wk[idx - 8192];
    else                  v = wv[idx - 16384];
    unsigned short hi = f2bf(v);
    wh[idx] = hi;
    wl[idx] = f2bf(v - bf2f(hi));
}

// ---------------------------------------------------------------------------
// Kernel 1 (fused transpose+proj, SOFTWARE-PIPELINED): stage x chunk kc+1
// (issue loads BEFORE GEMM(kc), convert+write AFTER -- T14) so x-load
// latency hides under the 60-MFMA GEMM body. Staging pass p writes exactly
// the channel chunks GEMM iteration kc=p reads; read/write LDS slot sets are
// disjoint per row under the shared XOR swizzle, so the in-flight overlap is
// race-free with one barrier per kc. GEMM core, W path, epilogue unchanged.
// ---------------------------------------------------------------------------
#define PJ_XL 32768
#define PJ_VE 16384
__global__ __launch_bounds__(256, 2) void proj_kernel(
    const float* __restrict__ x,
    const unsigned short* __restrict__ wh, const unsigned short* __restrict__ wl,
    const float* __restrict__ bq, const float* __restrict__ bk,
    const float* __restrict__ bv,
    unsigned short* __restrict__ qh, unsigned short* __restrict__ ql,
    unsigned short* __restrict__ kh, unsigned short* __restrict__ kl,
    unsigned short* __restrict__ vt)
{
    __shared__ __align__(16) unsigned char smem[65536];
    const int t    = threadIdx.x;
    const int lane = t & 63;
    const int w    = t >> 6;
    const int l16  = lane & 15;
    const int quad = lane >> 4;
    const int b    = blockIdx.x >> 6;
    const int n0   = (blockIdx.x & 63) << 6;

    const float* xB = x + (size_t)b * 256 * NN + n0;
    const int n = lane;                 // pixel row 0..63 (this thread's row)

    // ---- prologue: stage chunk 0 (loads exposed once) ----
    {
        int cc = w;                     // p=0: cc = 0*4 + w
        float v[8];
        #pragma unroll
        for (int j = 0; j < 8; ++j)
            v[j] = xB[(size_t)(cc * 8 + j) * NN + n];
        us8 h8, l8;
        #pragma unroll
        for (int j = 0; j < 8; ++j) {
            unsigned short hi = f2bf(v[j]);
            h8[j] = hi;
            l8[j] = f2bf(v[j] - bf2f(hi));
        }
        int off = n * 512 + ((cc ^ (n & 7)) << 4);
        *(us8*)(smem + off) = h8;
        *(us8*)(smem + PJ_XL + off) = l8;
    }
    __syncthreads();

    f32x4 acc[5][4] = {};
    #pragma unroll 1
    for (int kc = 0; kc < 8; ++kc) {
        // ---- issue loads for chunk kc+1 (consumed after GEMM below) ----
        float vnext[8];
        if (kc < 7) {
            int cc = (kc + 1) * 4 + w;
            #pragma unroll
            for (int j = 0; j < 8; ++j)
                vnext[j] = xB[(size_t)(cc * 8 + j) * NN + n];
        }

        // ---- GEMM(kc): hides the vnext load latency ----
        bf16x8 ah[5], al[5];
        #pragma unroll
        for (int i = 0; i < 5; ++i) {
            int och = (w * 5 + i) * 16 + l16;
            ah[i] = *(const bf16x8*)(wh + och * 256 + kc * 32 + quad * 8);
            al[i] = *(const bf16x8*)(wl + och * 256 + kc * 32 + quad * 8);
        }
        #pragma unroll
        for (int nt = 0; nt < 4; ++nt) {
            int roff = (nt * 16 + l16) * 512 + (((kc * 4 + quad) ^ (l16 & 7)) * 16);
            bf16x8 bh = *(const bf16x8*)(smem + roff);
            bf16x8 bl = *(const bf16x8*)(smem + PJ_XL + roff);
            #pragma unroll
            for (int i = 0; i < 5; ++i) {
                acc[i][nt] = MFMA16(ah[i], bh, acc[i][nt]);
                acc[i][nt] = MFMA16(al[i], bh, acc[i][nt]);
                acc[i][nt] = MFMA16(ah[i], bl, acc[i][nt]);
            }
        }

        // ---- convert + write chunk kc+1 (disjoint LDS slots vs GEMM kc) ----
        if (kc < 7) {
            int cc = (kc + 1) * 4 + w;
            us8 h8, l8;
            #pragma unroll
            for (int j = 0; j < 8; ++j) {
                unsigned short hi = f2bf(vnext[j]);
                h8[j] = hi;
                l8[j] = f2bf(vnext[j] - bf2f(hi));
            }
            int off = n * 512 + ((cc ^ (n & 7)) << 4);
            *(us8*)(smem + off) = h8;
            *(us8*)(smem + PJ_XL + off) = l8;
        }
        __syncthreads();   // chunk kc+1 visible before GEMM(kc+1)
    }

    #pragma unroll
    for (int i = 0; i < 5; ++i) {
        int tile = w * 5 + i;
        if (tile < 4) {
            #pragma unroll
            for (int r = 0; r < 4; ++r) {
                int och = tile * 16 + quad * 4 + r;
                float bias = (och < 32) ? bq[och] : bk[och - 32];
                int arr = (och < 32) ? 0 : 2;
                int oq = och & 31;
                #pragma unroll
                for (int nt = 0; nt < 4; ++nt) {
                    float val = acc[i][nt][r] + bias;
                    if (och < 32) val *= LOG2E;
                    unsigned short hi = f2bf(val);
                    unsigned short lo = f2bf(val - bf2f(hi));
                    *(unsigned short*)(smem + arr * 4096 + (nt * 16 + l16) * 64 + oq * 2) = hi;
                    *(unsigned short*)(smem + (arr + 1) * 4096 + (nt * 16 + l16) * 64 + oq * 2) = lo;
                }
            }
        } else {
            #pragma unroll
            for (int r = 0; r < 4; ++r) {
                int voch = tile * 16 + quad * 4 + r - 64;
                float bias = bv[voch];
                #pragma unroll
                for (int nt = 0; nt < 4; ++nt) {
                    *(unsigned short*)(smem + PJ_VE + voch * 136 + (nt * 16 + l16) * 2)
                        = f2bf(acc[i][nt][r] + bias);
                }
            }
        }
    }
    __syncthreads();

    {
        unsigned short* dsts[4] = { qh, ql, kh, kl };
        int arr = t >> 6, nn = t & 63;
        unsigned short* dst = dsts[arr] + ((size_t)b * NN + n0 + nn) * 32;
        #pragma unroll
        for (int i = 0; i < 4; ++i)
            *(us8*)(dst + i * 8) = *(const us8*)(smem + arr * 4096 + nn * 64 + i * 16);
    }
    #pragma unroll
    for (int p = 0; p < 4; ++p) {
        int voch = p * 64 + (t >> 2), piece = t & 3;
        unsigned short* dst = vt + ((size_t)b * CH + voch) * NN + n0 + piece * 16;
        *(us8*)(dst)     = *(const us8*)(smem + PJ_VE + voch * 136 + piece * 32);
        *(us8*)(dst + 8) = *(const us8*)(smem + PJ_VE + voch * 136 + piece * 32 + 16);
    }
}

// ---------------------------------------------------------------------------
// Kernel 3: MFMA flash attention -- ROUND-10/11 VERBATIM (proven 122.5-124us,
// FETCH 12.3MB): 512 blocks x 256 thr, b=blockIdx&7, 80KB LDS, V dbuf
// 2x32KB, P dbuf 2x8KB, ONE barrier/tile; E 12-MFMA setprio cluster then
// VALU cluster; PV 16 hoisted LDS reads then one 32-MFMA setprio cluster.
// ---------------------------------------------------------------------------
#define A_P0 0          // P buffer 0: 64 rows x 128B
#define A_P1 8192       // P buffer 1
#define A_V0 16384      // V buffer 0: 256ch x 128B
#define A_V1 49152      // V buffer 1
#define A_SM 16384      // 256 floats, aliases V0 (post-loop only)

__global__ __launch_bounds__(256, 2) void attn_kernel(
    const unsigned short* __restrict__ qh, const unsigned short* __restrict__ ql,
    const unsigned short* __restrict__ kh, const unsigned short* __restrict__ kl,
    const unsigned short* __restrict__ vt, const float* __restrict__ gptr,
    float* __restrict__ out)
{
    __shared__ __align__(16) unsigned char smem[81920];
    const int t    = threadIdx.x;
    const int lane = t & 63;
    const int w    = t >> 6;
    const int l16  = lane & 15;
    const int quad = lane >> 4;
    const int b    = blockIdx.x & 7;
    const int n0   = (blockIdx.x >> 3) << 6;

    // Q B-frags (hi/lo); Q pre-scaled by log2e
    bf16x8 qhA[4], qlA[4];
    #pragma unroll
    for (int qt = 0; qt < 4; ++qt) {
        size_t row = (size_t)b * NN + n0 + qt * 16 + l16;
        qhA[qt] = *(const bf16x8*)(qh + row * 32 + quad * 8);
        qlA[qt] = *(const bf16x8*)(ql + row * 32 + quad * 8);
    }

    // K A-frag base: wave w owns keys w*16..+15 of each 64-key tile
    const unsigned short* khbase = kh + ((size_t)b * NN + w * 16 + l16) * 32 + quad * 8;
    const unsigned short* klbase = kl + ((size_t)b * NN + w * 16 + l16) * 32 + quad * 8;
    const unsigned char*  vtB    = (const unsigned char*)(vt + (size_t)b * CH * NN);

    // hoisted per-thread stage addresses
    const unsigned char* vsrc[8];
    int vlds[8];
    #pragma unroll
    for (int j = 0; j < 8; ++j) {
        int idx = j * 256 + t;
        int r = idx >> 3, cl = idx & 7;
        int cg = cl ^ (r & 7);
        vsrc[j] = vtB + (size_t)r * 8192 + cg * 16;   // tile-0 base
        vlds[j] = idx * 16;
    }
    // P-write offset (lane-constant): row = query l16, key chunk XOR row&7
    const int poff = l16 * 128 + ((((w << 1) | (quad >> 1)) ^ (l16 & 7)) << 4)
                   + ((quad & 1) << 3);

    f32x4 acc[4][4] = {};
    float S[4] = {};

    // prologue: K(0) regs first, then stage V(0) into V0
    bf16x8 kch = *(const bf16x8*)(khbase);
    bf16x8 kcl = *(const bf16x8*)(klbase);
    #pragma unroll
    for (int j = 0; j < 8; ++j)
        gload16(vsrc[j], smem + A_V0 + vlds[j]);

    #pragma unroll 1
    for (int tile = 0; tile < 64; ++tile) {
        unsigned char* P = smem + ((tile & 1) ? A_P1 : A_P0);

        // ---- E, MFMA cluster: all 12 MFMAs back-to-back ----
        f32x4 e4[4];
        __builtin_amdgcn_s_setprio(1);
        #pragma unroll
        for (int qt = 0; qt < 4; ++qt) {
            f32x4 e = { 0.f, 0.f, 0.f, 0.f };
            e = MFMA16(kch, qhA[qt], e);
            e = MFMA16(kch, qlA[qt], e);
            e = MFMA16(kcl, qhA[qt], e);
            e4[qt] = e;
        }
        __builtin_amdgcn_s_setprio(0);

        // ---- E, VALU cluster: exp2 / pack / S / P-write ----
        #pragma unroll
        for (int qt = 0; qt < 4; ++qt) {
            float p0 = exp2f(e4[qt][0]), p1 = exp2f(e4[qt][1]);
            float p2 = exp2f(e4[qt][2]), p3 = exp2f(e4[qt][3]);
            unsigned int u01, u23;
            asm("v_cvt_pk_bf16_f32 %0, %1, %2" : "=v"(u01) : "v"(p0), "v"(p1));
            asm("v_cvt_pk_bf16_f32 %0, %1, %2" : "=v"(u23) : "v"(p2), "v"(p3));
            // S sums the rounded values actually stored in P
            S[qt] += (__uint_as_float(u01 << 16) + __uint_as_float(u01 & 0xffff0000u))
                   + (__uint_as_float(u23 << 16) + __uint_as_float(u23 & 0xffff0000u));
            int2 pk2 = { (int)u01, (int)u23 };
            *(int2*)(P + qt * 2048 + poff) = pk2;
        }

        __syncthreads();   // P(tile) + V(tile) ready; prev PV reads drained

        // ---- post-barrier VMEM issue (consumed after NEXT barrier) ----
        const int m1 = ((tile + 1) & 63) * 64;
        bf16x8 knh = *(const bf16x8*)(khbase + (size_t)m1 * 32);
        bf16x8 knl = *(const bf16x8*)(klbase + (size_t)m1 * 32);
        if (tile < 63) {
            unsigned char* vdst = smem + ((tile & 1) ? A_V0 : A_V1);
            #pragma unroll
            for (int j = 0; j < 8; ++j) {
                vsrc[j] += 128;
                gload16(vsrc[j], vdst + vlds[j]);
            }
        }

        // ---- PV: hoist ALL 16 LDS reads, then one 32-MFMA cluster ----
        const unsigned char* VB = smem + ((tile & 1) ? A_V1 : A_V0);
        bf16x8 af0[4], af1[4], bf0[4], bf1[4];
        #pragma unroll
        for (int qt = 0; qt < 4; ++qt) {
            int row = qt * 16 + l16;
            af0[qt] = *(const bf16x8*)(P + row * 128
                                         + (((0 * 4 + quad) ^ (l16 & 7)) << 4));
            af1[qt] = *(const bf16x8*)(P + row * 128
                                         + (((1 * 4 + quad) ^ (l16 & 7)) << 4));
        }
        #pragma unroll
        for (int ct = 0; ct < 4; ++ct) {
            int vrow = w * 64 + ct * 16 + l16;
            bf0[ct] = *(const bf16x8*)(VB + vrow * 128
                                          + (((0 * 4 + quad) ^ (l16 & 7)) << 4));
            bf1[ct] = *(const bf16x8*)(VB + vrow * 128
                                          + (((1 * 4 + quad) ^ (l16 & 7)) << 4));
        }
        __builtin_amdgcn_s_setprio(1);
        #pragma unroll
        for (int qt = 0; qt < 4; ++qt)
            #pragma unroll
            for (int ct = 0; ct < 4; ++ct)
                acc[qt][ct] = MFMA16(af0[qt], bf0[ct], acc[qt][ct]);
        #pragma unroll
        for (int qt = 0; qt < 4; ++qt)
            #pragma unroll
            for (int ct = 0; ct < 4; ++ct)
                acc[qt][ct] = MFMA16(af1[qt], bf1[ct], acc[qt][ct]);
        __builtin_amdgcn_s_setprio(0);

        kch = knh;
        kcl = knl;
    }

    // S: reduce over quads (same query in lanes l16+16q), then across waves
    #pragma unroll
    for (int mask = 16; mask <= 32; mask <<= 1)
        #pragma unroll
        for (int qt = 0; qt < 4; ++qt)
            S[qt] += __shfl_xor(S[qt], mask);
    float* SM = (float*)(smem + A_SM);
    if (quad == 0) {
        #pragma unroll
        for (int qt = 0; qt < 4; ++qt)
            SM[w * 64 + qt * 16 + l16] = S[qt];
    }
    __syncthreads();

    const float g1 = 1.f + gptr[0];
    float* ob = out + (size_t)b * CH * NN;
    #pragma unroll
    for (int qt = 0; qt < 4; ++qt) {
        float is[4];
        #pragma unroll
        for (int r = 0; r < 4; ++r) {
            int qi = qt * 16 + quad * 4 + r;
            float Sf = SM[qi] + SM[64 + qi] + SM[128 + qi] + SM[192 + qi];
            is[r] = g1 / Sf;
        }
        #pragma unroll
        for (int ct = 0; ct < 4; ++ct) {
            float4 o4;
            o4.x = floorf(acc[qt][ct][0] * is[0] * 256.f) * 0.00390625f;
            o4.y = floorf(acc[qt][ct][1] * is[1] * 256.f) * 0.00390625f;
            o4.z = floorf(acc[qt][ct][2] * is[2] * 256.f) * 0.00390625f;
            o4.w = floorf(acc[qt][ct][3] * is[3] * 256.f) * 0.00390625f;
            *(float4*)(ob + (size_t)(w * 64 + ct * 16 + l16) * NN
                          + n0 + qt * 16 + quad * 4) = o4;
        }
    }
}

// ---------------------------------------------------------------------------
extern "C" void kernel_launch(void* const* d_in, const int* in_sizes, int n_in,
                              void* d_out, int out_size, void* d_ws, size_t ws_size,
                              hipStream_t stream) {
    const float* x  = (const float*)d_in[0];
    const float* wq = (const float*)d_in[1];
    const float* bq = (const float*)d_in[2];
    const float* wk = (const float*)d_in[3];
    const float* bk = (const float*)d_in[4];
    const float* wv = (const float*)d_in[5];
    const float* bv = (const float*)d_in[6];
    const float* gm = (const float*)d_in[7];
    float* out = (float*)d_out;

    unsigned short* ws = (unsigned short*)d_ws;
    const size_t WSZ = 320 * 256;               // 81,920
    const size_t QSZ = (size_t)BB * NN * 32;    // 1,048,576
    const size_t XSZ = (size_t)BB * NN * 256;   // 8,388,608
    unsigned short* wh = ws;
    unsigned short* wl = wh + WSZ;
    unsigned short* qh = wl + WSZ;
    unsigned short* ql = qh + QSZ;
    unsigned short* kh = ql + QSZ;
    unsigned short* kl = kh + QSZ;
    unsigned short* vt = kl + QSZ;              // vt size XSZ

    wsplit_kernel<<<320, 256, 0, stream>>>(wq, wk, wv, wh, wl);
    proj_kernel<<<512, 256, 0, stream>>>(x, wh, wl, bq, bk, bv,
                                         qh, ql, kh, kl, vt);
    attn_kernel<<<512, 256, 0, stream>>>(qh, ql, kh, kl, vt, gm, out);
}